// Round 1
// baseline (1345.984 us; speedup 1.0000x reference)
//
#include <hip/hip_runtime.h>
#include <math.h>
#include <stdint.h>

#define B_    32
#define S_    4096
#define H_    16
#define KVL   512
#define ROPED 64
#define NOPED 128
#define QKD_  192
#define VD_   128
#define QIN_  1536
#define HID_  2048
#define CD    576           // KV_LORA + ROPE
#define SCALE_ 0.07216878364870322f   // 192^-0.5
#define CS    256           // s-chunk per attention block
#define NCH   16            // S_/CS

// ---------- exact fp8 e4m3fn round-trip (RNE, saturating) ----------
__device__ __forceinline__ float fp8_rt(float x) {
  x = fminf(448.f, fmaxf(-448.f, x));
  float a = fabsf(x);
  float r;
  if (a < 0x1p-10f) {
    r = 0.f;
  } else {
    unsigned int b = __float_as_uint(a);
    int E = (int)(b >> 23) - 127;              // a is a normal float here
    int eq = (E < -6) ? -9 : (E - 3);          // quantum exponent (subnormal step 2^-9)
    float q  = __uint_as_float((unsigned int)(eq  + 127) << 23);
    float qi = __uint_as_float((unsigned int)(-eq + 127) << 23);
    r = rintf(a * qi) * q;                     // exact scaling; rintf = RNE
  }
  return (x < 0.f) ? -r : r;
}
__device__ __forceinline__ float deq(float w, float scale) {
  return fp8_rt(w * scale) / scale;
}

// ---------- tensor-wide amax of |W_K|, |W_V| ----------
__global__ void k_amax(const float* __restrict__ WK, const float* __restrict__ WV,
                       unsigned int* __restrict__ amax_bits) {
  int tid = blockIdx.x * blockDim.x + threadIdx.x;
  int stride = gridDim.x * blockDim.x;
  float mk = 0.f, mv = 0.f;
  const int N = H_ * KVL * NOPED;  // 1,048,576 (same count for both tensors)
  for (int i = tid; i < N; i += stride) {
    mk = fmaxf(mk, fabsf(WK[i]));
    mv = fmaxf(mv, fabsf(WV[i]));
  }
  for (int m = 32; m; m >>= 1) {
    mk = fmaxf(mk, __shfl_xor(mk, m));
    mv = fmaxf(mv, __shfl_xor(mv, m));
  }
  if ((threadIdx.x & 63) == 0) {
    atomicMax(&amax_bits[0], __float_as_uint(mk));
    atomicMax(&amax_bits[1], __float_as_uint(mv));
  }
}

// ---------- generic C(32xN) = A(32xK) @ B(KxN), fp32, 16-col tiles ----------
template<int K, int N>
__global__ __launch_bounds__(256) void k_gemm32(const float* __restrict__ A,
                                                const float* __restrict__ Bm,
                                                float* __restrict__ C) {
  __shared__ __align__(16) float As[32 * 132];  // pad 132: bank-spread broadcasts
  int n0 = blockIdx.x * 16;
  int t = threadIdx.x;
  int n = t & 15, bg = t >> 4;                  // bg 0..15, rows bg and bg+16
  float acc0 = 0.f, acc1 = 0.f;
  for (int k0 = 0; k0 < K; k0 += 128) {
    __syncthreads();
#pragma unroll
    for (int i = 0; i < 4; ++i) {
      int f = t + i * 256;                      // 1024 float4 per stage
      int row = f >> 5, c4 = (f & 31) * 4;
      *(float4*)&As[row * 132 + c4] = *(const float4*)&A[(size_t)row * K + k0 + c4];
    }
    __syncthreads();
#pragma unroll 4
    for (int kk = 0; kk < 128; ++kk) {
      float wv = Bm[(size_t)(k0 + kk) * N + n0 + n];
      acc0 += As[bg * 132 + kk] * wv;
      acc1 += As[(bg + 16) * 132 + kk] * wv;
    }
  }
  C[(size_t)bg * N + n0 + n] = acc0;
  C[(size_t)(bg + 16) * N + n0 + n] = acc1;
}

// ---------- prep: rope(k_pe)->kv_cache[b,len], rope(q_pe)*SCALE->qf[...,512:576] ----------
__global__ void k_prep(const float* __restrict__ kc, const float* __restrict__ kpe,
                       const int* __restrict__ lens, const float* __restrict__ qp,
                       float* __restrict__ kv, float* __restrict__ qf) {
  int b = blockIdx.x, t = threadIdx.x;
  int len = lens[b];
  float* row = kv + ((size_t)b * S_ + len) * CD;
  for (int i = t; i < KVL; i += 64) row[i] = kc[b * KVL + i];
  if (t < 32) {
    float x = (float)t * (1.f / 32.f);
    float inv = 1.f / powf(10000.f, x);
    float ang = (float)len * inv;
    float sn, csv;
    sincosf(ang, &sn, &csv);
    {
      float x1 = kpe[b * ROPED + t], x2 = kpe[b * ROPED + 32 + t];
      row[KVL + t]      = x1 * csv - x2 * sn;
      row[KVL + 32 + t] = x2 * csv + x1 * sn;
    }
    for (int h = 0; h < H_; ++h) {
      const float* qb = qp + (size_t)(b * H_ + h) * QKD_;
      float x1 = qb[NOPED + t], x2 = qb[NOPED + 32 + t];
      float* qo = qf + (size_t)(b * H_ + h) * CD;
      qo[KVL + t]      = (x1 * csv - x2 * sn) * SCALE_;
      qo[KVL + 32 + t] = (x2 * csv + x1 * sn) * SCALE_;
    }
  }
}

// ---------- ql_nope: qf[b,h,c] = SCALE * sum_d qp_nope[b,h,d] * deq(W_K[h,c,d]) ----------
__global__ __launch_bounds__(256) void k_qlnope(const float* __restrict__ qp,
                                                const float* __restrict__ WK,
                                                const unsigned int* __restrict__ amax_bits,
                                                float* __restrict__ qf) {
  __shared__ __align__(16) float A[32 * 132];
  int h = blockIdx.x, c0 = blockIdx.y * 128;
  int t = threadIdx.x;
  float scale = 448.f / fmaxf(__uint_as_float(amax_bits[0]), 1e-10f);
#pragma unroll
  for (int i = 0; i < 4; ++i) {                  // stage qp[0:32][h][0:128]
    int f = t + i * 256;
    int b = f >> 5, c4 = (f & 31) * 4;
    *(float4*)&A[b * 132 + c4] = *(const float4*)&qp[(size_t)(b * H_ + h) * QKD_ + c4];
  }
  __syncthreads();
  int c = t & 127, bg = t >> 7;                  // bg 0..1, rows bg + 2i
  const float* wrow = WK + ((size_t)h * KVL + c0 + c) * NOPED;
  float acc[16];
#pragma unroll
  for (int i = 0; i < 16; ++i) acc[i] = 0.f;
  for (int d4 = 0; d4 < 32; ++d4) {
    float4 w4 = *(const float4*)&wrow[d4 * 4];
    float w0 = deq(w4.x, scale), w1 = deq(w4.y, scale);
    float w2 = deq(w4.z, scale), w3 = deq(w4.w, scale);
#pragma unroll
    for (int i = 0; i < 16; ++i) {
      const float* a = &A[(bg + 2 * i) * 132 + d4 * 4];
      acc[i] += a[0] * w0 + a[1] * w1 + a[2] * w2 + a[3] * w3;
    }
  }
#pragma unroll
  for (int i = 0; i < 16; ++i)
    qf[(size_t)((bg + 2 * i) * H_ + h) * CD + c0 + c] = acc[i] * SCALE_;
}

// ---------- flash-decode attention over s-chunks ----------
__global__ __launch_bounds__(256) void k_attn(const float* __restrict__ kv,
                                              const float* __restrict__ qf,
                                              const int* __restrict__ lens,
                                              float* __restrict__ pml,
                                              float* __restrict__ po) {
  __shared__ __align__(16) float kvt[64 * CD];   // 147456 B, XOR-swizzled
  __shared__ float sl[H_ * 64];                  // 4 KB: scores then p
  int b = blockIdx.x, ch = blockIdx.y;
  int L = lens[b] + 1;
  int start = ch * CS;
  if (start >= L) return;
  int end = min(start + CS, L);
  int t = threadIdx.x;
  int w = t >> 6, l = t & 63;
  const float* qfb = qf + (size_t)b * H_ * CD;
  float m[4], lr[4], o[4][8];
#pragma unroll
  for (int i = 0; i < 4; ++i) {
    m[i] = -INFINITY; lr[i] = 0.f;
#pragma unroll
    for (int k = 0; k < 8; ++k) o[i][k] = 0.f;
  }
  for (int s0 = start; s0 < end; s0 += 64) {
    int nr = min(64, end - s0);
    __syncthreads();
    // stage: wave w loads rows w, w+4, ... ; XOR swizzle c^( (r&7)<<2 ) on dword idx
    for (int r = w; r < nr; r += 4) {
      int xs = (r & 7) << 2;
      const float* g = kv + ((size_t)b * S_ + s0 + r) * CD;
      float* dst = &kvt[r * CD];
      float4 v0 = *(const float4*)&g[4 * l];
      *(float4*)&dst[(4 * l) ^ xs] = v0;
      float4 v1 = *(const float4*)&g[4 * (64 + l)];
      *(float4*)&dst[(4 * (64 + l)) ^ xs] = v1;
      if (l < 16) {
        float4 v2 = *(const float4*)&g[4 * (128 + l)];
        *(float4*)&dst[(4 * (128 + l)) ^ xs] = v2;
      }
    }
    for (int i = t; i < H_ * 64; i += 256) sl[i] = 0.f;
    __syncthreads();
    // score: lane = row l, wave covers dims [w*144, w*144+144)
    if (l < nr) {
      float part[16];
#pragma unroll
      for (int h = 0; h < 16; ++h) part[h] = 0.f;
      int xs = (l & 7) << 2;
      const float* myrow = &kvt[l * CD];
      int dbeg = w * 144, dend = dbeg + 144;
      for (int d0 = dbeg; d0 < dend; d0 += 8) {
        float4 ka = *(const float4*)&myrow[d0 ^ xs];
        float4 kb = *(const float4*)&myrow[(d0 + 4) ^ xs];
#pragma unroll
        for (int h = 0; h < 16; ++h) {
          const float* qh = &qfb[h * CD + d0];   // wave-uniform address
          part[h] += qh[0] * ka.x + qh[1] * ka.y + qh[2] * ka.z + qh[3] * ka.w
                   + qh[4] * kb.x + qh[5] * kb.y + qh[6] * kb.z + qh[7] * kb.w;
        }
      }
#pragma unroll
      for (int h = 0; h < 16; ++h) atomicAdd(&sl[h * 64 + l], part[h]);
    }
    __syncthreads();
    // softmax update + PV for this wave's 4 heads
    int h0 = w * 4;
#pragma unroll
    for (int i = 0; i < 4; ++i) {
      int h = h0 + i;
      float sc = (l < nr) ? sl[h * 64 + l] : -INFINITY;
      float mt = sc;
      for (int mm = 1; mm < 64; mm <<= 1) mt = fmaxf(mt, __shfl_xor(mt, mm));
      float mn = fmaxf(m[i], mt);
      float ef = expf(m[i] - mn);
      float p = (l < nr) ? expf(sc - mn) : 0.f;
      float ps = p;
      for (int mm = 1; mm < 64; mm <<= 1) ps += __shfl_xor(ps, mm);
      lr[i] = lr[i] * ef + ps;
      m[i] = mn;
#pragma unroll
      for (int k = 0; k < 8; ++k) o[i][k] *= ef;
      sl[h * 64 + l] = p;                        // overwrite score with p
    }
    for (int s4 = 0; s4 < nr; s4 += 4) {
      float4 p4[4];
#pragma unroll
      for (int i = 0; i < 4; ++i) p4[i] = *(const float4*)&sl[(h0 + i) * 64 + s4];
#pragma unroll
      for (int r = 0; r < 4; ++r) {
        if (s4 + r < nr) {
          int srow = s4 + r;
          int xs = (srow & 7) << 2;
          const float* kr = &kvt[srow * CD];
          float4 va = *(const float4*)&kr[(4 * l) ^ xs];
          float4 vb = *(const float4*)&kr[(256 + 4 * l) ^ xs];
#pragma unroll
          for (int i = 0; i < 4; ++i) {
            float pv = (r == 0) ? p4[i].x : (r == 1) ? p4[i].y : (r == 2) ? p4[i].z : p4[i].w;
            o[i][0] += pv * va.x; o[i][1] += pv * va.y;
            o[i][2] += pv * va.z; o[i][3] += pv * va.w;
            o[i][4] += pv * vb.x; o[i][5] += pv * vb.y;
            o[i][6] += pv * vb.z; o[i][7] += pv * vb.w;
          }
        }
      }
    }
  }
  // write partials
#pragma unroll
  for (int i = 0; i < 4; ++i) {
    int h = w * 4 + i;
    size_t base = ((size_t)(b * NCH + ch) * H_ + h);
    if (l == 0) { pml[base * 2 + 0] = m[i]; pml[base * 2 + 1] = lr[i]; }
    float4 va, vb;
    va.x = o[i][0]; va.y = o[i][1]; va.z = o[i][2]; va.w = o[i][3];
    vb.x = o[i][4]; vb.y = o[i][5]; vb.z = o[i][6]; vb.w = o[i][7];
    *(float4*)&po[base * 512 + 4 * l] = va;
    *(float4*)&po[base * 512 + 256 + 4 * l] = vb;
  }
}

// ---------- combine chunk partials -> o_final[b,h,512] ----------
__global__ void k_combine(const float* __restrict__ pml, const float* __restrict__ po,
                          const int* __restrict__ lens, float* __restrict__ of) {
  int bh = blockIdx.x;
  int b = bh >> 4, h = bh & 15;
  int l = threadIdx.x;  // 64
  int L = lens[b] + 1;
  int nc = (L + CS - 1) / CS;
  float M = -INFINITY;
  for (int j = 0; j < nc; ++j)
    M = fmaxf(M, pml[(((size_t)b * NCH + j) * H_ + h) * 2]);
  float Ls = 0.f;
  float O[8];
#pragma unroll
  for (int k = 0; k < 8; ++k) O[k] = 0.f;
  for (int j = 0; j < nc; ++j) {
    size_t base = ((size_t)b * NCH + j) * H_ + h;
    float f = expf(pml[base * 2] - M);
    Ls += f * pml[base * 2 + 1];
    float4 a = *(const float4*)&po[base * 512 + 4 * l];
    float4 c = *(const float4*)&po[base * 512 + 256 + 4 * l];
    O[0] += f * a.x; O[1] += f * a.y; O[2] += f * a.z; O[3] += f * a.w;
    O[4] += f * c.x; O[5] += f * c.y; O[6] += f * c.z; O[7] += f * c.w;
  }
  float inv = 1.f / Ls;
  float4 va, vb;
  va.x = O[0] * inv; va.y = O[1] * inv; va.z = O[2] * inv; va.w = O[3] * inv;
  vb.x = O[4] * inv; vb.y = O[5] * inv; vb.z = O[6] * inv; vb.w = O[7] * inv;
  float* dst = of + ((size_t)b * H_ + h) * 512;
  *(float4*)&dst[4 * l] = va;
  *(float4*)&dst[256 + 4 * l] = vb;
}

// ---------- t[b, h*128+v] = sum_c o_final[b,h,c] * deq(W_V[h,v,c]) ----------
__global__ __launch_bounds__(256) void k_t(const float* __restrict__ of,
                                           const float* __restrict__ WV,
                                           const unsigned int* __restrict__ amax_bits,
                                           float* __restrict__ tb) {
  __shared__ __align__(16) float A[32 * 516];
  int h = blockIdx.x, v0 = blockIdx.y * 32;
  int t = threadIdx.x;
  float scale = 448.f / fmaxf(__uint_as_float(amax_bits[1]), 1e-10f);
#pragma unroll
  for (int i = 0; i < 16; ++i) {                 // stage o_final[0:32][h][0:512]
    int f = t + i * 256;
    int b = f >> 7, c4 = (f & 127) * 4;
    *(float4*)&A[b * 516 + c4] = *(const float4*)&of[((size_t)b * H_ + h) * 512 + c4];
  }
  __syncthreads();
  int v = t & 31, bg = t >> 5;                   // rows bg + 8i
  const float* wrow = WV + ((size_t)h * VD_ + v0 + v) * KVL;
  float acc[4] = {0.f, 0.f, 0.f, 0.f};
  for (int c4 = 0; c4 < 128; ++c4) {
    float4 w4 = *(const float4*)&wrow[c4 * 4];
    float w0 = deq(w4.x, scale), w1 = deq(w4.y, scale);
    float w2 = deq(w4.z, scale), w3 = deq(w4.w, scale);
#pragma unroll
    for (int i = 0; i < 4; ++i) {
      const float* a = &A[(bg + 8 * i) * 516 + c4 * 4];
      acc[i] += a[0] * w0 + a[1] * w1 + a[2] * w2 + a[3] * w3;
    }
  }
#pragma unroll
  for (int i = 0; i < 4; ++i)
    tb[(size_t)(bg + 8 * i) * HID_ + h * VD_ + v0 + v] = acc[i];
}

extern "C" void kernel_launch(void* const* d_in, const int* in_sizes, int n_in,
                              void* d_out, int out_size, void* d_ws, size_t ws_size,
                              hipStream_t stream) {
  const float* q   = (const float*)d_in[0];
  const float* kc  = (const float*)d_in[1];
  const float* kpe = (const float*)d_in[2];
  float*       kv  = (float*)d_in[3];    // mutated: scatter of new token row
  const float* Wq  = (const float*)d_in[4];
  const float* WK  = (const float*)d_in[5];
  const float* WV  = (const float*)d_in[6];
  const float* Wo  = (const float*)d_in[7];
  const int*  lens = (const int*)d_in[8];

  float* ws = (float*)d_ws;
  unsigned int* amax_bits = (unsigned int*)d_ws;
  float* qp  = ws + 64;                                  // 32*16*192
  float* qf  = qp + (size_t)B_ * H_ * QKD_;              // 32*16*576
  float* pml = qf + (size_t)B_ * H_ * CD;                // 32*16*16*2
  float* po  = pml + (size_t)B_ * NCH * H_ * 2;          // 32*16*16*512
  float* of  = po + (size_t)B_ * NCH * H_ * 512;         // 32*16*512
  float* tb  = of + (size_t)B_ * H_ * 512;               // 32*2048

  hipMemsetAsync(d_ws, 0, 256, stream);
  k_amax<<<256, 256, 0, stream>>>(WK, WV, amax_bits);
  k_gemm32<QIN_, H_ * QKD_><<<(H_ * QKD_) / 16, 256, 0, stream>>>(q, Wq, qp);
  k_prep<<<B_, 64, 0, stream>>>(kc, kpe, lens, qp, kv, qf);
  k_qlnope<<<dim3(H_, 4), 256, 0, stream>>>(qp, WK, amax_bits, qf);
  k_attn<<<dim3(B_, NCH), 256, 0, stream>>>(kv, qf, lens, pml, po);
  k_combine<<<B_ * H_, 64, 0, stream>>>(pml, po, lens, of);
  k_t<<<dim3(H_, 4), 256, 0, stream>>>(of, WV, amax_bits, tb);
  k_gemm32<HID_, HID_><<<HID_ / 16, 256, 0, stream>>>(tb, Wo, (float*)d_out);
}

// Round 2
// 623.599 us; speedup vs baseline: 2.1584x; 2.1584x over previous
//
#include <hip/hip_runtime.h>
#include <math.h>
#include <stdint.h>

#define B_    32
#define S_    4096
#define H_    16
#define KVL   512
#define ROPED 64
#define NOPED 128
#define QKD_  192
#define VD_   128
#define QIN_  1536
#define HID_  2048
#define CD    576
#define SCALE_ 0.07216878364870322f   // 192^-0.5
#define CS2   128                     // s-chunk per attention block
#define NCH2  32                      // S_/CS2
#define TR    16                      // kv tile rows
#define KVP   580                     // padded LDS row stride (580%32==4 -> 2-way max)

// ---------- exact fp8 e4m3fn round-trip (RNE, saturating) ----------
__device__ __forceinline__ float fp8_rt(float x) {
  x = fminf(448.f, fmaxf(-448.f, x));
  float a = fabsf(x);
  float r;
  if (a < 0x1p-10f) {
    r = 0.f;
  } else {
    unsigned int b = __float_as_uint(a);
    int E = (int)(b >> 23) - 127;
    int eq = (E < -6) ? -9 : (E - 3);
    float q  = __uint_as_float((unsigned int)(eq  + 127) << 23);
    float qi = __uint_as_float((unsigned int)(-eq + 127) << 23);
    r = rintf(a * qi) * q;
  }
  return (x < 0.f) ? -r : r;
}

// ---------- tensor-wide amax of |W_K|, |W_V| ----------
__global__ void k_amax(const float* __restrict__ WK, const float* __restrict__ WV,
                       unsigned int* __restrict__ amax_bits) {
  int tid = blockIdx.x * blockDim.x + threadIdx.x;
  int stride = gridDim.x * blockDim.x;
  float mk = 0.f, mv = 0.f;
  const int N = H_ * KVL * NOPED;
  for (int i = tid; i < N; i += stride) {
    mk = fmaxf(mk, fabsf(WK[i]));
    mv = fmaxf(mv, fabsf(WV[i]));
  }
  for (int m = 32; m; m >>= 1) {
    mk = fmaxf(mk, __shfl_xor(mk, m));
    mv = fmaxf(mv, __shfl_xor(mv, m));
  }
  if ((threadIdx.x & 63) == 0) {
    atomicMax(&amax_bits[0], __float_as_uint(mk));
    atomicMax(&amax_bits[1], __float_as_uint(mv));
  }
}

// ---------- C(32xN) += A(32xK_chunk) @ B, K split across blocks, atomic ----------
template<int K, int N>
__global__ __launch_bounds__(256) void k_gemmA(const float* __restrict__ A,
                                               const float* __restrict__ Bm,
                                               float* __restrict__ C) {
  __shared__ __align__(16) float As[32 * 260];
  int t = threadIdx.x;
  int k0 = blockIdx.y * 256;
  int n = blockIdx.x * 64 + (t & 63);
  int bg = t >> 6;
#pragma unroll
  for (int i = 0; i < 8; ++i) {                 // 2048 float4 = 32 rows x 256 k
    int f = t + i * 256;
    int row = f >> 6, j = f & 63;
    *(float4*)&As[row * 260 + 4 * j] = *(const float4*)&A[(size_t)row * K + k0 + 4 * j];
  }
  __syncthreads();
  const float* Bp = Bm + (size_t)k0 * N + n;
  float acc[8] = {0.f, 0.f, 0.f, 0.f, 0.f, 0.f, 0.f, 0.f};
#pragma unroll 4
  for (int kk = 0; kk < 256; ++kk) {
    float wv = Bp[(size_t)kk * N];
#pragma unroll
    for (int i = 0; i < 8; ++i)
      acc[i] += As[(bg + 4 * i) * 260 + kk] * wv;
  }
#pragma unroll
  for (int i = 0; i < 8; ++i)
    atomicAdd(&C[(size_t)(bg + 4 * i) * N + n], acc[i]);
}

// ---------- prep: rope(k_pe)->kv_cache[b,len], rope(q_pe)*SCALE->qf[...,512:576] ----------
__global__ void k_prep(const float* __restrict__ kc, const float* __restrict__ kpe,
                       const int* __restrict__ lens, const float* __restrict__ qp,
                       float* __restrict__ kv, float* __restrict__ qf) {
  int b = blockIdx.x, t = threadIdx.x;
  int len = lens[b];
  float* row = kv + ((size_t)b * S_ + len) * CD;
  for (int i = t; i < KVL; i += 64) row[i] = kc[b * KVL + i];
  if (t < 32) {
    float x = (float)t * (1.f / 32.f);
    float inv = 1.f / powf(10000.f, x);
    float ang = (float)len * inv;
    float sn, csv;
    sincosf(ang, &sn, &csv);
    {
      float x1 = kpe[b * ROPED + t], x2 = kpe[b * ROPED + 32 + t];
      row[KVL + t]      = x1 * csv - x2 * sn;
      row[KVL + 32 + t] = x2 * csv + x1 * sn;
    }
    for (int h = 0; h < H_; ++h) {
      const float* qb = qp + (size_t)(b * H_ + h) * QKD_;
      float x1 = qb[NOPED + t], x2 = qb[NOPED + 32 + t];
      float* qo = qf + (size_t)(b * H_ + h) * CD;
      qo[KVL + t]      = (x1 * csv - x2 * sn) * SCALE_;
      qo[KVL + 32 + t] = (x2 * csv + x1 * sn) * SCALE_;
    }
  }
}

// ---------- ql_nope via LDS-transposed W_K ----------
__global__ __launch_bounds__(256) void k_qlnope(const float* __restrict__ qp,
                                                const float* __restrict__ WK,
                                                const unsigned int* __restrict__ amax_bits,
                                                float* __restrict__ qf) {
  __shared__ __align__(16) float A[32 * 132];
  __shared__ float Wl[128 * 65];                // [d][c], c-tile 64
  int h = blockIdx.x, c0 = blockIdx.y * 64;
  int t = threadIdx.x;
  float scale = 448.f / fmaxf(__uint_as_float(amax_bits[0]), 1e-10f);
#pragma unroll
  for (int i = 0; i < 4; ++i) {                 // qp[0:32][h][0:128]
    int f = t + i * 256;
    int bb = f >> 5, j = f & 31;
    *(float4*)&A[bb * 132 + 4 * j] = *(const float4*)&qp[(size_t)(bb * H_ + h) * QKD_ + 4 * j];
  }
#pragma unroll
  for (int i = 0; i < 8; ++i) {                 // W[h][c0+cr][0:128] -> Wl[d][cr], dequant
    int cr = (t >> 5) + 8 * i, dj = t & 31;
    float4 wv = *(const float4*)&WK[((size_t)h * KVL + c0 + cr) * NOPED + 4 * dj];
    Wl[(4 * dj + 0) * 65 + cr] = fp8_rt(wv.x * scale) / scale;
    Wl[(4 * dj + 1) * 65 + cr] = fp8_rt(wv.y * scale) / scale;
    Wl[(4 * dj + 2) * 65 + cr] = fp8_rt(wv.z * scale) / scale;
    Wl[(4 * dj + 3) * 65 + cr] = fp8_rt(wv.w * scale) / scale;
  }
  __syncthreads();
  int c = t & 63, bg = t >> 6;
  float acc[8] = {0.f, 0.f, 0.f, 0.f, 0.f, 0.f, 0.f, 0.f};
#pragma unroll 4
  for (int d = 0; d < 128; ++d) {
    float w = Wl[d * 65 + c];
#pragma unroll
    for (int i = 0; i < 8; ++i)
      acc[i] += A[(bg + 4 * i) * 132 + d] * w;
  }
#pragma unroll
  for (int i = 0; i < 8; ++i)
    qf[(size_t)((bg + 4 * i) * H_ + h) * CD + c0 + c] = acc[i] * SCALE_;
}

// ---------- flash-decode attention, 16-row tiles, reg-staged prefetch ----------
__global__ __launch_bounds__(256, 2) void k_attn(const float* __restrict__ kv,
                                                 const float* __restrict__ qf,
                                                 const int* __restrict__ lens,
                                                 float* __restrict__ pml,
                                                 float* __restrict__ po) {
  __shared__ __align__(16) float kvt[TR * KVP];   // 37120 B
  __shared__ __align__(16) float qlds[H_ * KVP];  // 37120 B
  __shared__ float sl[H_ * 20];                   // p values
  __shared__ float slef[H_];                      // rescale factors
  int b = blockIdx.x, ch = blockIdx.y;
  int L = lens[b] + 1;
  int start = ch * CS2;
  if (start >= L) return;
  int end = min(start + CS2, L);
  int t = threadIdx.x;
  int l = t & 63, w = t >> 6;
  int r_s = t & 15, h_s = t >> 4;                 // score role: (row, head)
  int row_st = t >> 4, j0 = t & 15;               // staging role

  { // stage q once
    const float* src = qf + ((size_t)b * H_ + h_s) * CD;
    float* dst = &qlds[h_s * KVP];
#pragma unroll
    for (int i = 0; i < 9; ++i) {
      int j = j0 + 16 * i;
      *(float4*)&dst[4 * j] = *(const float4*)&src[4 * j];
    }
  }

  float m = -INFINITY, lr = 0.f;
  float o[4][8];
#pragma unroll
  for (int i = 0; i < 4; ++i)
#pragma unroll
    for (int k = 0; k < 8; ++k) o[i][k] = 0.f;

  float4 st[9];
  int nt = (end - start + TR - 1) / TR;

  // load tile 0
  {
    int r = start + row_st;
    if (r < end) {
      const float* g = kv + ((size_t)b * S_ + r) * CD;
#pragma unroll
      for (int i = 0; i < 9; ++i) st[i] = *(const float4*)&g[4 * (j0 + 16 * i)];
    } else {
#pragma unroll
      for (int i = 0; i < 9; ++i) st[i] = make_float4(0.f, 0.f, 0.f, 0.f);
    }
  }
  { // write tile 0
    float* dst = &kvt[row_st * KVP];
#pragma unroll
    for (int i = 0; i < 9; ++i) *(float4*)&dst[4 * (j0 + 16 * i)] = st[i];
  }
  __syncthreads();

  for (int ti = 0; ti < nt; ++ti) {
    int s0 = start + ti * TR;
    int nr = min(TR, end - s0);
    if (ti + 1 < nt) {                            // prefetch next tile into regs
      int r = s0 + TR + row_st;
      if (r < end) {
        const float* g = kv + ((size_t)b * S_ + r) * CD;
#pragma unroll
        for (int i = 0; i < 9; ++i) st[i] = *(const float4*)&g[4 * (j0 + 16 * i)];
      } else {
#pragma unroll
        for (int i = 0; i < 9; ++i) st[i] = make_float4(0.f, 0.f, 0.f, 0.f);
      }
    }
    // ---- score: full 576-dot per (r_s, h_s) thread ----
    float s;
    {
      const float* kr = &kvt[r_s * KVP];
      const float* qr = &qlds[h_s * KVP];
      float a0 = 0.f, a1 = 0.f, a2 = 0.f, a3 = 0.f;
#pragma unroll 4
      for (int d = 0; d < 576; d += 16) {
        float4 ka = *(const float4*)&kr[d];
        float4 qa = *(const float4*)&qr[d];
        float4 kb = *(const float4*)&kr[d + 4];
        float4 qb = *(const float4*)&qr[d + 4];
        float4 kc2 = *(const float4*)&kr[d + 8];
        float4 qc2 = *(const float4*)&qr[d + 8];
        float4 kd = *(const float4*)&kr[d + 12];
        float4 qd = *(const float4*)&qr[d + 12];
        a0 += ka.x * qa.x + ka.y * qa.y + ka.z * qa.z + ka.w * qa.w;
        a1 += kb.x * qb.x + kb.y * qb.y + kb.z * qb.z + kb.w * qb.w;
        a2 += kc2.x * qc2.x + kc2.y * qc2.y + kc2.z * qc2.z + kc2.w * qc2.w;
        a3 += kd.x * qd.x + kd.y * qd.y + kd.z * qd.z + kd.w * qd.w;
      }
      s = (a0 + a1) + (a2 + a3);
      if (r_s >= nr) s = -INFINITY;
    }
    // ---- online softmax over 16-lane group (same head) ----
    float mt = s;
#pragma unroll
    for (int mm = 1; mm < 16; mm <<= 1) mt = fmaxf(mt, __shfl_xor(mt, mm));
    float mn = fmaxf(m, mt);
    float ef = expf(m - mn);
    float p = expf(s - mn);
    float ps = p;
#pragma unroll
    for (int mm = 1; mm < 16; mm <<= 1) ps += __shfl_xor(ps, mm);
    lr = lr * ef + ps;
    m = mn;
    sl[h_s * 20 + r_s] = p;                       // same-wave consumers only
    if (r_s == 0) slef[h_s] = ef;
    __threadfence_block();
    // ---- PV: wave w -> heads 4w..4w+3, lanes on c ----
#pragma unroll
    for (int i = 0; i < 4; ++i) {
      float efi = slef[4 * w + i];
#pragma unroll
      for (int k = 0; k < 8; ++k) o[i][k] *= efi;
    }
    for (int r4 = 0; r4 < nr; r4 += 4) {
      float4 p4[4];
#pragma unroll
      for (int i = 0; i < 4; ++i) p4[i] = *(const float4*)&sl[(4 * w + i) * 20 + r4];
#pragma unroll
      for (int rr = 0; rr < 4; ++rr) {
        const float* kr2 = &kvt[(r4 + rr) * KVP];
        float4 va = *(const float4*)&kr2[4 * l];
        float4 vb = *(const float4*)&kr2[256 + 4 * l];
#pragma unroll
        for (int i = 0; i < 4; ++i) {
          float pv = (rr == 0) ? p4[i].x : (rr == 1) ? p4[i].y : (rr == 2) ? p4[i].z : p4[i].w;
          o[i][0] += pv * va.x; o[i][1] += pv * va.y;
          o[i][2] += pv * va.z; o[i][3] += pv * va.w;
          o[i][4] += pv * vb.x; o[i][5] += pv * vb.y;
          o[i][6] += pv * vb.z; o[i][7] += pv * vb.w;
        }
      }
    }
    __syncthreads();
    if (ti + 1 < nt) {                            // write prefetched tile
      float* dst = &kvt[row_st * KVP];
#pragma unroll
      for (int i = 0; i < 9; ++i) *(float4*)&dst[4 * (j0 + 16 * i)] = st[i];
    }
    __syncthreads();
  }
  // ---- write partials ----
  size_t base0 = (size_t)(b * NCH2 + ch) * H_;
  if (r_s == 0) {
    size_t base = base0 + h_s;
    pml[base * 2 + 0] = m;
    pml[base * 2 + 1] = lr;
  }
#pragma unroll
  for (int i = 0; i < 4; ++i) {
    size_t base = base0 + 4 * w + i;
    float4 va, vb;
    va.x = o[i][0]; va.y = o[i][1]; va.z = o[i][2]; va.w = o[i][3];
    vb.x = o[i][4]; vb.y = o[i][5]; vb.z = o[i][6]; vb.w = o[i][7];
    *(float4*)&po[base * 512 + 4 * l] = va;
    *(float4*)&po[base * 512 + 256 + 4 * l] = vb;
  }
}

// ---------- combine chunk partials -> o_final[b,h,512] ----------
__global__ void k_combine(const float* __restrict__ pml, const float* __restrict__ po,
                          const int* __restrict__ lens, float* __restrict__ of) {
  int bh = blockIdx.x;
  int b = bh >> 4, h = bh & 15;
  int l = threadIdx.x;  // 64
  int L = lens[b] + 1;
  int nc = (L + CS2 - 1) / CS2;
  float M = -INFINITY;
  for (int j = 0; j < nc; ++j)
    M = fmaxf(M, pml[(((size_t)b * NCH2 + j) * H_ + h) * 2]);
  float Ls = 0.f;
  float O[8];
#pragma unroll
  for (int k = 0; k < 8; ++k) O[k] = 0.f;
  for (int j = 0; j < nc; ++j) {
    size_t base = ((size_t)b * NCH2 + j) * H_ + h;
    float f = expf(pml[base * 2] - M);
    Ls += f * pml[base * 2 + 1];
    float4 a = *(const float4*)&po[base * 512 + 4 * l];
    float4 c = *(const float4*)&po[base * 512 + 256 + 4 * l];
    O[0] += f * a.x; O[1] += f * a.y; O[2] += f * a.z; O[3] += f * a.w;
    O[4] += f * c.x; O[5] += f * c.y; O[6] += f * c.z; O[7] += f * c.w;
  }
  float inv = 1.f / Ls;
  float4 va, vb;
  va.x = O[0] * inv; va.y = O[1] * inv; va.z = O[2] * inv; va.w = O[3] * inv;
  vb.x = O[4] * inv; vb.y = O[5] * inv; vb.z = O[6] * inv; vb.w = O[7] * inv;
  float* dst = of + ((size_t)b * H_ + h) * 512;
  *(float4*)&dst[4 * l] = va;
  *(float4*)&dst[256 + 4 * l] = vb;
}

// ---------- t = o_final @ W_V^T (per head), LDS-transposed W, c-split atomic ----------
__global__ __launch_bounds__(256) void k_t(const float* __restrict__ of,
                                           const float* __restrict__ WV,
                                           const unsigned int* __restrict__ amax_bits,
                                           float* __restrict__ tb) {
  __shared__ __align__(16) float A[32 * 132];
  __shared__ float Wl[128 * 65];                // [c][v], v-tile 64
  int h = blockIdx.x;
  int vt = blockIdx.y & 1, cc = blockIdx.y >> 1;
  int v0 = vt * 64, c0 = cc * 128;
  int t = threadIdx.x;
  float scale = 448.f / fmaxf(__uint_as_float(amax_bits[1]), 1e-10f);
#pragma unroll
  for (int i = 0; i < 4; ++i) {                 // of[0:32][h][c0:c0+128]
    int f = t + i * 256;
    int bb = f >> 5, j = f & 31;
    *(float4*)&A[bb * 132 + 4 * j] = *(const float4*)&of[((size_t)bb * H_ + h) * 512 + c0 + 4 * j];
  }
#pragma unroll
  for (int i = 0; i < 8; ++i) {                 // WV[h][v0+vr][c0:c0+128] -> Wl[c][vr]
    int vr = (t >> 5) + 8 * i, cj = t & 31;
    float4 wv = *(const float4*)&WV[((size_t)h * VD_ + v0 + vr) * KVL + c0 + 4 * cj];
    Wl[(4 * cj + 0) * 65 + vr] = fp8_rt(wv.x * scale) / scale;
    Wl[(4 * cj + 1) * 65 + vr] = fp8_rt(wv.y * scale) / scale;
    Wl[(4 * cj + 2) * 65 + vr] = fp8_rt(wv.z * scale) / scale;
    Wl[(4 * cj + 3) * 65 + vr] = fp8_rt(wv.w * scale) / scale;
  }
  __syncthreads();
  int v = t & 63, bg = t >> 6;
  float acc[8] = {0.f, 0.f, 0.f, 0.f, 0.f, 0.f, 0.f, 0.f};
#pragma unroll 4
  for (int c = 0; c < 128; ++c) {
    float wv = Wl[c * 65 + v];
#pragma unroll
    for (int i = 0; i < 8; ++i)
      acc[i] += A[(bg + 4 * i) * 132 + c] * wv;
  }
#pragma unroll
  for (int i = 0; i < 8; ++i)
    atomicAdd(&tb[(size_t)(bg + 4 * i) * HID_ + h * VD_ + v0 + v], acc[i]);
}

extern "C" void kernel_launch(void* const* d_in, const int* in_sizes, int n_in,
                              void* d_out, int out_size, void* d_ws, size_t ws_size,
                              hipStream_t stream) {
  const float* q   = (const float*)d_in[0];
  const float* kc  = (const float*)d_in[1];
  const float* kpe = (const float*)d_in[2];
  float*       kv  = (float*)d_in[3];
  const float* Wq  = (const float*)d_in[4];
  const float* WK  = (const float*)d_in[5];
  const float* WV  = (const float*)d_in[6];
  const float* Wo  = (const float*)d_in[7];
  const int*  lens = (const int*)d_in[8];

  float* ws = (float*)d_ws;
  unsigned int* amax_bits = (unsigned int*)d_ws;
  float* qp  = ws + 64;                                   // 32*16*192  = 98304
  float* qf  = qp + (size_t)B_ * H_ * QKD_;               // 32*16*576  = 294912
  float* pml = qf + (size_t)B_ * H_ * CD;                 // 32*32*16*2 = 32768
  float* po  = pml + (size_t)B_ * NCH2 * H_ * 2;          // 32*32*16*512
  float* of  = po + (size_t)B_ * NCH2 * H_ * 512;         // 32*16*512
  float* tb  = of + (size_t)B_ * H_ * 512;                // 32*2048

  hipMemsetAsync(d_ws, 0, (64 + (size_t)B_ * H_ * QKD_) * 4, stream);  // amax + qp
  hipMemsetAsync(tb, 0, (size_t)B_ * HID_ * 4, stream);
  hipMemsetAsync(d_out, 0, (size_t)B_ * HID_ * 4, stream);

  k_amax<<<256, 256, 0, stream>>>(WK, WV, amax_bits);
  k_gemmA<QIN_, H_ * QKD_><<<dim3((H_ * QKD_) / 64, QIN_ / 256), 256, 0, stream>>>(q, Wq, qp);
  k_prep<<<B_, 64, 0, stream>>>(kc, kpe, lens, qp, kv, qf);
  k_qlnope<<<dim3(H_, 8), 256, 0, stream>>>(qp, WK, amax_bits, qf);
  k_attn<<<dim3(B_, NCH2), 256, 0, stream>>>(kv, qf, lens, pml, po);
  k_combine<<<B_ * H_, 64, 0, stream>>>(pml, po, lens, of);
  k_t<<<dim3(H_, 8), 256, 0, stream>>>(of, WV, amax_bits, tb);
  k_gemmA<HID_, HID_><<<dim3(HID_ / 64, HID_ / 256), 256, 0, stream>>>(tb, Wo, (float*)d_out);
}